// Round 2
// baseline (145.467 us; speedup 1.0000x reference)
//
#include <hip/hip_runtime.h>
#include <hip/hip_bf16.h>

#define NN 8192
#define CC 64
#define KSPLIT 8
#define KCHUNK (NN / KSPLIT)   // 1024
#define BK 64
#define NSTEPS (KCHUNK / BK)   // 16

typedef __bf16 bf16;
typedef __bf16 bf16x8 __attribute__((ext_vector_type(8)));
typedef float f32x4 __attribute__((ext_vector_type(4)));
typedef unsigned short us8 __attribute__((ext_vector_type(8)));

// ---------------- kernel 1: softmax rows of Y -> Ys (f32), YsT (bf16, transposed), nwc partials
__global__ __launch_bounds__(256) void k1_softmax(const float* __restrict__ Yin,
                                                  float* __restrict__ Ys,
                                                  unsigned short* __restrict__ YsT,
                                                  float* __restrict__ nwc_part) {
    __shared__ float lds_t[64][65];   // [col][row_local], padded
    __shared__ float nwc_lds[4][64];
    const int t = threadIdx.x;
    const int w = t >> 6, lane = t & 63;
    const int b = blockIdx.x;
    const int r0 = b * 64;
    float nwc_acc = 0.f;
    for (int it = 0; it < 16; ++it) {
        const int rl = it * 4 + w;
        const int row = r0 + rl;
        float y = Yin[row * CC + lane];
        float mx = y;
        #pragma unroll
        for (int m = 32; m >= 1; m >>= 1) mx = fmaxf(mx, __shfl_xor(mx, m, 64));
        float e = __expf(y - mx);
        float s = e;
        #pragma unroll
        for (int m = 32; m >= 1; m >>= 1) s += __shfl_xor(s, m, 64);
        float ys = e / s;
        Ys[row * CC + lane] = ys;
        lds_t[lane][rl] = ys;
        nwc_acc += ys;
    }
    nwc_lds[w][lane] = nwc_acc;
    __syncthreads();
    if (t < 64)
        nwc_part[b * 64 + t] = nwc_lds[0][t] + nwc_lds[1][t] + nwc_lds[2][t] + nwc_lds[3][t];
    // write YsT bf16: thread t handles col c = t>>2, 16 rows starting q*16
    const int c = t >> 2, q = t & 3;
    unsigned short tmp[16];
    #pragma unroll
    for (int i = 0; i < 16; ++i) {
        float v = lds_t[c][q * 16 + i];
        tmp[i] = __builtin_bit_cast(unsigned short, (__bf16)v);
    }
    us8* dst = (us8*)(&YsT[(size_t)c * NN + r0 + q * 16]);
    dst[0] = *(us8*)(&tmp[0]);
    dst[1] = *(us8*)(&tmp[8]);
}

// ---------------- kernel 2: Bpart[kb] = A[:, kchunk] * Ys[kchunk, :]  (bf16 MFMA, no LDS)
// Each wave owns 16 output rows; A fragments loaded directly from global
// (16 rows x one 128B line per load inst, each line touched exactly once),
// B fragments from L2-resident YsT. One-step software prefetch on A.
__global__ __launch_bounds__(256) void k2_gemm(const float* __restrict__ A,
                                               const unsigned short* __restrict__ YsT,
                                               float* __restrict__ Bpart,
                                               float* __restrict__ edges_part) {
    __shared__ float ered[4];
    const int t = threadIdx.x;
    const int w = t >> 6, lane = t & 63;
    const int rb = blockIdx.x;   // 0..127 row block
    const int kb = blockIdx.y;   // 0..7   k split
    const int row0 = rb * 64;
    const int k0 = kb * KCHUNK;
    const int lq = lane >> 4;        // 0..3  (k-chunk within 32-slice)
    const int l15 = lane & 15;       // row / col within 16-tile

    // A fragment base: row = row0 + w*16 + l15, k = k0 + lq*8 (+kk*32 +s*64)
    const float* pa = A + (size_t)(row0 + w * 16 + l15) * NN + k0 + lq * 8;
    // B fragment base: col = t4*16 + l15, k = k0 + lq*8 (+kk*32 +s*64)
    const unsigned short* pb0 = YsT + (size_t)l15 * NN + k0 + lq * 8;

    f32x4 acc[4] = {};
    float esum = 0.f;

    // prologue: load step 0 A fragments (fp32)
    float4 c0 = *(const float4*)(pa + 0);
    float4 c1 = *(const float4*)(pa + 4);
    float4 c2 = *(const float4*)(pa + 32);
    float4 c3 = *(const float4*)(pa + 36);

    #pragma unroll 2
    for (int s = 0; s < NSTEPS; ++s) {
        // prefetch next step's A (last iter: re-load current, discarded)
        const int offn = ((s + 1 < NSTEPS) ? (s + 1) : s) * BK;
        const float4 n0 = *(const float4*)(pa + offn + 0);
        const float4 n1 = *(const float4*)(pa + offn + 4);
        const float4 n2 = *(const float4*)(pa + offn + 32);
        const float4 n3 = *(const float4*)(pa + offn + 36);

        // B fragments for this step (L2-resident, short latency)
        const int offb = s * BK;
        bf16x8 b0[4], b1[4];
        #pragma unroll
        for (int t4 = 0; t4 < 4; ++t4) {
            const unsigned short* pb = pb0 + (size_t)t4 * 16 * NN + offb;
            b0[t4] = *(const bf16x8*)(pb);
            b1[t4] = *(const bf16x8*)(pb + 32);
        }

        // edge sum over this step's A values (each A elem counted exactly once grid-wide)
        esum += (c0.x + c0.y + c0.z + c0.w) + (c1.x + c1.y + c1.z + c1.w)
              + (c2.x + c2.y + c2.z + c2.w) + (c3.x + c3.y + c3.z + c3.w);

        // convert to bf16 fragments
        bf16x8 a0, a1;
        a0[0] = (__bf16)c0.x; a0[1] = (__bf16)c0.y; a0[2] = (__bf16)c0.z; a0[3] = (__bf16)c0.w;
        a0[4] = (__bf16)c1.x; a0[5] = (__bf16)c1.y; a0[6] = (__bf16)c1.z; a0[7] = (__bf16)c1.w;
        a1[0] = (__bf16)c2.x; a1[1] = (__bf16)c2.y; a1[2] = (__bf16)c2.z; a1[3] = (__bf16)c2.w;
        a1[4] = (__bf16)c3.x; a1[5] = (__bf16)c3.y; a1[6] = (__bf16)c3.z; a1[7] = (__bf16)c3.w;

        #pragma unroll
        for (int t4 = 0; t4 < 4; ++t4)
            acc[t4] = __builtin_amdgcn_mfma_f32_16x16x32_bf16(a0, b0[t4], acc[t4], 0, 0, 0);
        #pragma unroll
        for (int t4 = 0; t4 < 4; ++t4)
            acc[t4] = __builtin_amdgcn_mfma_f32_16x16x32_bf16(a1, b1[t4], acc[t4], 0, 0, 0);

        c0 = n0; c1 = n1; c2 = n2; c3 = n3;
    }

    // --- write partial B: Bpart[kb][row][col]
    const size_t base = ((size_t)kb * NN + row0) * CC;
    #pragma unroll
    for (int t4 = 0; t4 < 4; ++t4) {
        const int col = t4 * 16 + l15;
        #pragma unroll
        for (int r = 0; r < 4; ++r) {
            const int grow = w * 16 + lq * 4 + r;   // D layout: row=(lane>>4)*4+reg
            Bpart[base + (size_t)grow * CC + col] = acc[t4][r];
        }
    }
    // --- edge sum reduction (deterministic)
    #pragma unroll
    for (int m = 32; m >= 1; m >>= 1) esum += __shfl_xor(esum, m, 64);
    if (lane == 0) ered[w] = esum;
    __syncthreads();
    if (t == 0) edges_part[rb * KSPLIT + kb] = ered[0] + ered[1] + ered[2] + ered[3];
}

// ---------------- kernel 3: partial M over 64-row chunks: Mpart[b] = Ys[chunk]^T * B[chunk]
__global__ __launch_bounds__(256) void k3_mpart(const float* __restrict__ Bpart,
                                                const float* __restrict__ Ys,
                                                float* __restrict__ Mpart) {
    __shared__ float bl[4096];   // B rows [64][64]
    __shared__ float yl[4096];   // Ys rows [64][64]
    const int t = threadIdx.x;
    const int b = blockIdx.x;    // 0..127
    const int r0 = b * 64;
    for (int k = 0; k < 16; ++k) {
        const int e = k * 256 + t;
        const int i = e >> 6, c = e & 63;
        const size_t off = ((size_t)(r0 + i)) * CC + c;
        float s = 0.f;
        #pragma unroll
        for (int p = 0; p < KSPLIT; ++p) s += Bpart[(size_t)p * NN * CC + off];
        bl[e] = s;
        yl[e] = Ys[off];
    }
    __syncthreads();
    const int w = t >> 6, lane = t & 63;
    float acc[16];
    #pragma unroll
    for (int k = 0; k < 16; ++k) acc[k] = 0.f;
    for (int i = 0; i < 64; ++i) {
        const float bv = bl[i * 64 + lane];
        #pragma unroll
        for (int k = 0; k < 16; ++k)
            acc[k] += yl[i * 64 + 4 * k + w] * bv;   // c1 = 4k + w uniform per wave -> broadcast
    }
    #pragma unroll
    for (int k = 0; k < 16; ++k)
        Mpart[(size_t)b * 4096 + k * 256 + t] = acc[k];   // index == c1*64 + c2
}

// ---------------- kernel 4: reduce Mpart -> M[64][64]
__global__ __launch_bounds__(256) void k4_reduce(const float* __restrict__ Mpart,
                                                 float* __restrict__ M) {
    const int e = blockIdx.x * 256 + threadIdx.x;   // grid 16
    float s = 0.f;
    for (int b = 0; b < 128; ++b) s += Mpart[(size_t)b * 4096 + e];
    M[e] = s;
}

// ---------------- kernel 5: final scalar
__global__ __launch_bounds__(256) void k5_final(const float* __restrict__ M,
                                                const float* __restrict__ nwc_part,
                                                const float* __restrict__ edges_part,
                                                float* __restrict__ out) {
    __shared__ float red[256];
    const int t = threadIdx.x;
    float se = 0.f, st = 0.f, sc = 0.f;
    for (int i = t; i < 128 * KSPLIT; i += 256) se += edges_part[i];
    for (int e = t; e < 4096; e += 256) {
        const int c1 = e >> 6, c2 = e & 63;
        if (c2 > c1) st += M[e];
    }
    if (t < 64) {
        float nwc = 0.f;
        for (int b = 0; b < 128; ++b) nwc += nwc_part[b * 64 + t];
        const float me = (nwc * (nwc - 1.0f) + 1e-8f) * 0.5f;
        sc = M[t * 65] / me;
    }
    // three block reductions
    red[t] = se; __syncthreads();
    for (int s = 128; s >= 1; s >>= 1) { if (t < s) red[t] += red[t + s]; __syncthreads(); }
    const float tot_e = red[0]; __syncthreads();
    red[t] = st; __syncthreads();
    for (int s = 128; s >= 1; s >>= 1) { if (t < s) red[t] += red[t + s]; __syncthreads(); }
    const float tot_triu = red[0]; __syncthreads();
    red[t] = sc; __syncthreads();
    for (int s = 128; s >= 1; s >>= 1) { if (t < s) red[t] += red[t + s]; __syncthreads(); }
    const float cohesion = red[0];
    if (t == 0)
        out[0] = -cohesion + tot_triu / (tot_e + 1e-9f);
}

extern "C" void kernel_launch(void* const* d_in, const int* in_sizes, int n_in,
                              void* d_out, int out_size, void* d_ws, size_t ws_size,
                              hipStream_t stream) {
    const float* A   = (const float*)d_in[0];
    const float* Yin = (const float*)d_in[1];
    float* out = (float*)d_out;
    char* ws = (char*)d_ws;
    // workspace layout (bytes)
    float*          Ys         = (float*)(ws + 0);                  // 2 MB
    unsigned short* YsT        = (unsigned short*)(ws + 2097152);   // 1 MB
    float*          nwc_part   = (float*)(ws + 3145728);            // 32 KB
    float*          edges_part = (float*)(ws + 3178496);            // 4 KB
    float*          Bpart      = (float*)(ws + 4194304);            // 16 MB
    float*          Mpart      = (float*)(ws + 20971520);           // 2 MB
    float*          M          = (float*)(ws + 23068672);           // 16 KB

    k1_softmax<<<128, 256, 0, stream>>>(Yin, Ys, YsT, nwc_part);
    k2_gemm<<<dim3(128, KSPLIT), 256, 0, stream>>>(A, YsT, Bpart, edges_part);
    k3_mpart<<<128, 256, 0, stream>>>(Bpart, Ys, Mpart);
    k4_reduce<<<16, 256, 0, stream>>>(Mpart, M);
    k5_final<<<1, 256, 0, stream>>>(M, nwc_part, edges_part, out);
}

// Round 3
// 132.389 us; speedup vs baseline: 1.0988x; 1.0988x over previous
//
#include <hip/hip_runtime.h>
#include <hip/hip_bf16.h>

#define NN 8192
#define CC 64
#define KSPLIT 8
#define KCHUNK (NN / KSPLIT)   // 1024
#define BK 64
#define NSTEPS (KCHUNK / BK)   // 16

typedef __bf16 bf16;
typedef __bf16 bf16x8 __attribute__((ext_vector_type(8)));
typedef float f32x4 __attribute__((ext_vector_type(4)));
typedef unsigned short us8 __attribute__((ext_vector_type(8)));

// ---------------- kernel 1: softmax rows of Y -> Ys (f32), YsT (bf16, transposed), nwc partials
__global__ __launch_bounds__(256) void k1_softmax(const float* __restrict__ Yin,
                                                  float* __restrict__ Ys,
                                                  unsigned short* __restrict__ YsT,
                                                  float* __restrict__ nwc_part) {
    __shared__ float lds_t[64][65];   // [col][row_local], padded
    __shared__ float nwc_lds[4][64];
    const int t = threadIdx.x;
    const int w = t >> 6, lane = t & 63;
    const int b = blockIdx.x;
    const int r0 = b * 64;
    float nwc_acc = 0.f;
    for (int it = 0; it < 16; ++it) {
        const int rl = it * 4 + w;
        const int row = r0 + rl;
        float y = Yin[row * CC + lane];
        float mx = y;
        #pragma unroll
        for (int m = 32; m >= 1; m >>= 1) mx = fmaxf(mx, __shfl_xor(mx, m, 64));
        float e = __expf(y - mx);
        float s = e;
        #pragma unroll
        for (int m = 32; m >= 1; m >>= 1) s += __shfl_xor(s, m, 64);
        float ys = e / s;
        Ys[row * CC + lane] = ys;
        lds_t[lane][rl] = ys;
        nwc_acc += ys;
    }
    nwc_lds[w][lane] = nwc_acc;
    __syncthreads();
    if (t < 64)
        nwc_part[b * 64 + t] = nwc_lds[0][t] + nwc_lds[1][t] + nwc_lds[2][t] + nwc_lds[3][t];
    // write YsT bf16: thread t handles col c = t>>2, 16 rows starting q*16
    const int c = t >> 2, q = t & 3;
    unsigned short tmp[16];
    #pragma unroll
    for (int i = 0; i < 16; ++i) {
        float v = lds_t[c][q * 16 + i];
        tmp[i] = __builtin_bit_cast(unsigned short, (__bf16)v);
    }
    us8* dst = (us8*)(&YsT[(size_t)c * NN + r0 + q * 16]);
    dst[0] = *(us8*)(&tmp[0]);
    dst[1] = *(us8*)(&tmp[8]);
}

// ---------------- kernel 2: Bpart[kb] = A[:, kchunk] * Ys[kchunk, :]
// LDS staging via width-16 global_load_lds; swizzle applied by pre-swizzling
// the per-lane GLOBAL source (gload_lds writes linearly) and XOR-ing on read.
// A tile stays fp32 in LDS; convert to bf16 on the read side (each element
// read exactly once per block). Edge sum accumulated from read-side fragments.
__global__ __launch_bounds__(256) void k2_gemm(const float* __restrict__ A,
                                               const unsigned short* __restrict__ YsT,
                                               float* __restrict__ Bpart,
                                               float* __restrict__ edges_part) {
    __shared__ __align__(16) float ldsA[64 * 64];           // 16 KB, chunk-swizzled
    __shared__ __align__(16) unsigned short ldsB[64 * 64];  // 8 KB, chunk-swizzled
    __shared__ float ered[4];
    const int t = threadIdx.x;
    const int w = t >> 6, lane = t & 63;
    const int rb = blockIdx.x;   // 0..127 row block
    const int kb = blockIdx.y;   // 0..7   k split
    const int row0 = rb * 64;
    const int k0 = kb * KCHUNK;
    const int lq = lane >> 4;    // 0..3
    const int l15 = lane & 15;   // row/col within 16-tile

    // staging lane roles (gload_lds: lane j writes LDS base + j*16)
    const int ar  = lane >> 4;   // A: row offset within 4-row group
    const int ach = lane & 15;   // A: 16B chunk within row (4 floats)
    const int bc  = lane >> 3;   // B: col offset within 8-col group
    const int bch = lane & 7;    // B: 16B chunk within col (8 bf16)

    float esum = 0.f;
    f32x4 acc[4] = {};

    for (int s = 0; s < NSTEPS; ++s) {
        const int kbase = k0 + s * BK;
        __syncthreads();   // protect LDS from previous step's readers
        // --- stage A tile: 16 x global_load_lds_dwordx4 (1024B each), pre-swizzled source
        #pragma unroll
        for (int p = 0; p < 16; ++p) {
            const int r = p * 4 + ar;
            const float* src = A + (size_t)(row0 + r) * NN + kbase + ((ach ^ (r & 7)) << 2);
            __builtin_amdgcn_global_load_lds(
                (const __attribute__((address_space(1))) unsigned int*)src,
                (__attribute__((address_space(3))) unsigned int*)&ldsA[p * 256], 16, 0, 0);
        }
        // --- stage B tile: 8 x global_load_lds_dwordx4, pre-swizzled source
        #pragma unroll
        for (int q = 0; q < 8; ++q) {
            const int c = q * 8 + bc;
            const unsigned short* src = YsT + (size_t)c * NN + kbase + ((bch ^ (c & 7)) << 3);
            __builtin_amdgcn_global_load_lds(
                (const __attribute__((address_space(1))) unsigned int*)src,
                (__attribute__((address_space(3))) unsigned int*)&ldsB[q * 512], 16, 0, 0);
        }
        __syncthreads();   // drains vmcnt -> tiles ready
        // --- compute: 2 K-slices of 32, 4 col tiles
        #pragma unroll
        for (int kk = 0; kk < 2; ++kk) {
            const int r = w * 16 + l15;
            const int cc = kk * 8 + lq * 2;          // even global chunk
            const int ch0 = cc ^ (r & 7);            // LDS chunk holding global cc
            const f32x4 fa0 = *(const f32x4*)&ldsA[r * 64 + (ch0 << 2)];
            const f32x4 fa1 = *(const f32x4*)&ldsA[r * 64 + ((ch0 ^ 1) << 2)];
            esum += (fa0[0] + fa0[1] + fa0[2] + fa0[3]) + (fa1[0] + fa1[1] + fa1[2] + fa1[3]);
            bf16x8 a;
            a[0] = (__bf16)fa0[0]; a[1] = (__bf16)fa0[1]; a[2] = (__bf16)fa0[2]; a[3] = (__bf16)fa0[3];
            a[4] = (__bf16)fa1[0]; a[5] = (__bf16)fa1[1]; a[6] = (__bf16)fa1[2]; a[7] = (__bf16)fa1[3];
            #pragma unroll
            for (int t4 = 0; t4 < 4; ++t4) {
                const int col = t4 * 16 + l15;
                const int chB = (kk * 4 + lq) ^ (col & 7);
                const bf16x8 bb = *(const bf16x8*)&ldsB[col * 64 + (chB << 3)];
                acc[t4] = __builtin_amdgcn_mfma_f32_16x16x32_bf16(a, bb, acc[t4], 0, 0, 0);
            }
        }
    }

    // --- write partial B: Bpart[kb][row][col]
    const size_t base = ((size_t)kb * NN + row0) * CC;
    #pragma unroll
    for (int t4 = 0; t4 < 4; ++t4) {
        const int col = t4 * 16 + l15;
        #pragma unroll
        for (int r = 0; r < 4; ++r) {
            const int grow = w * 16 + lq * 4 + r;   // D layout: row=(lane>>4)*4+reg
            Bpart[base + (size_t)grow * CC + col] = acc[t4][r];
        }
    }
    // --- edge sum reduction (deterministic)
    #pragma unroll
    for (int m = 32; m >= 1; m >>= 1) esum += __shfl_xor(esum, m, 64);
    if (lane == 0) ered[w] = esum;
    __syncthreads();
    if (t == 0) edges_part[rb * KSPLIT + kb] = ered[0] + ered[1] + ered[2] + ered[3];
}

// ---------------- kernel 3: partial M over 64-row chunks: Mpart[b] = Ys[chunk]^T * B[chunk]
__global__ __launch_bounds__(256) void k3_mpart(const float* __restrict__ Bpart,
                                                const float* __restrict__ Ys,
                                                float* __restrict__ Mpart) {
    __shared__ float bl[4096];   // B rows [64][64]
    __shared__ float yl[4096];   // Ys rows [64][64]
    const int t = threadIdx.x;
    const int b = blockIdx.x;    // 0..127
    const int r0 = b * 64;
    for (int k = 0; k < 16; ++k) {
        const int e = k * 256 + t;
        const int i = e >> 6, c = e & 63;
        const size_t off = ((size_t)(r0 + i)) * CC + c;
        float s = 0.f;
        #pragma unroll
        for (int p = 0; p < KSPLIT; ++p) s += Bpart[(size_t)p * NN * CC + off];
        bl[e] = s;
        yl[e] = Ys[off];
    }
    __syncthreads();
    const int w = t >> 6, lane = t & 63;
    float acc[16];
    #pragma unroll
    for (int k = 0; k < 16; ++k) acc[k] = 0.f;
    for (int i = 0; i < 64; ++i) {
        const float bv = bl[i * 64 + lane];
        #pragma unroll
        for (int k = 0; k < 16; ++k)
            acc[k] += yl[i * 64 + 4 * k + w] * bv;   // c1 = 4k + w uniform per wave -> broadcast
    }
    #pragma unroll
    for (int k = 0; k < 16; ++k)
        Mpart[(size_t)b * 4096 + k * 256 + t] = acc[k];   // index == c1*64 + c2
}

// ---------------- kernel 4: reduce Mpart -> M[64][64]
__global__ __launch_bounds__(256) void k4_reduce(const float* __restrict__ Mpart,
                                                 float* __restrict__ M) {
    const int e = blockIdx.x * 256 + threadIdx.x;   // grid 16
    float s = 0.f;
    for (int b = 0; b < 128; ++b) s += Mpart[(size_t)b * 4096 + e];
    M[e] = s;
}

// ---------------- kernel 5: final scalar
__global__ __launch_bounds__(256) void k5_final(const float* __restrict__ M,
                                                const float* __restrict__ nwc_part,
                                                const float* __restrict__ edges_part,
                                                float* __restrict__ out) {
    __shared__ float red[256];
    const int t = threadIdx.x;
    float se = 0.f, st = 0.f, sc = 0.f;
    for (int i = t; i < 128 * KSPLIT; i += 256) se += edges_part[i];
    for (int e = t; e < 4096; e += 256) {
        const int c1 = e >> 6, c2 = e & 63;
        if (c2 > c1) st += M[e];
    }
    if (t < 64) {
        float nwc = 0.f;
        for (int b = 0; b < 128; ++b) nwc += nwc_part[b * 64 + t];
        const float me = (nwc * (nwc - 1.0f) + 1e-8f) * 0.5f;
        sc = M[t * 65] / me;
    }
    // three block reductions
    red[t] = se; __syncthreads();
    for (int s = 128; s >= 1; s >>= 1) { if (t < s) red[t] += red[t + s]; __syncthreads(); }
    const float tot_e = red[0]; __syncthreads();
    red[t] = st; __syncthreads();
    for (int s = 128; s >= 1; s >>= 1) { if (t < s) red[t] += red[t + s]; __syncthreads(); }
    const float tot_triu = red[0]; __syncthreads();
    red[t] = sc; __syncthreads();
    for (int s = 128; s >= 1; s >>= 1) { if (t < s) red[t] += red[t + s]; __syncthreads(); }
    const float cohesion = red[0];
    if (t == 0)
        out[0] = -cohesion + tot_triu / (tot_e + 1e-9f);
}

extern "C" void kernel_launch(void* const* d_in, const int* in_sizes, int n_in,
                              void* d_out, int out_size, void* d_ws, size_t ws_size,
                              hipStream_t stream) {
    const float* A   = (const float*)d_in[0];
    const float* Yin = (const float*)d_in[1];
    float* out = (float*)d_out;
    char* ws = (char*)d_ws;
    // workspace layout (bytes)
    float*          Ys         = (float*)(ws + 0);                  // 2 MB
    unsigned short* YsT        = (unsigned short*)(ws + 2097152);   // 1 MB
    float*          nwc_part   = (float*)(ws + 3145728);            // 32 KB
    float*          edges_part = (float*)(ws + 3178496);            // 4 KB
    float*          Bpart      = (float*)(ws + 4194304);            // 16 MB
    float*          Mpart      = (float*)(ws + 20971520);           // 2 MB
    float*          M          = (float*)(ws + 23068672);           // 16 KB

    k1_softmax<<<128, 256, 0, stream>>>(Yin, Ys, YsT, nwc_part);
    k2_gemm<<<dim3(128, KSPLIT), 256, 0, stream>>>(A, YsT, Bpart, edges_part);
    k3_mpart<<<128, 256, 0, stream>>>(Bpart, Ys, Mpart);
    k4_reduce<<<16, 256, 0, stream>>>(Mpart, M);
    k5_final<<<1, 256, 0, stream>>>(M, nwc_part, edges_part, out);
}

// Round 4
// 131.112 us; speedup vs baseline: 1.1095x; 1.0097x over previous
//
#include <hip/hip_runtime.h>
#include <hip/hip_bf16.h>

#define NN 8192
#define CC 64
#define KSPLIT 8
#define KCHUNK (NN / KSPLIT)   // 1024
#define BK 64
#define NSTEPS (KCHUNK / BK)   // 16

typedef __bf16 bf16;
typedef __bf16 bf16x8 __attribute__((ext_vector_type(8)));
typedef float f32x4 __attribute__((ext_vector_type(4)));
typedef unsigned short us8 __attribute__((ext_vector_type(8)));

// ---------------- kernel 1: softmax rows of Y -> Ys (f32), YsT (bf16, transposed), nwc partials
__global__ __launch_bounds__(256) void k1_softmax(const float* __restrict__ Yin,
                                                  float* __restrict__ Ys,
                                                  unsigned short* __restrict__ YsT,
                                                  float* __restrict__ nwc_part) {
    __shared__ float lds_t[64][65];   // [col][row_local], padded
    __shared__ float nwc_lds[4][64];
    const int t = threadIdx.x;
    const int w = t >> 6, lane = t & 63;
    const int b = blockIdx.x;
    const int r0 = b * 64;
    float nwc_acc = 0.f;
    for (int it = 0; it < 16; ++it) {
        const int rl = it * 4 + w;
        const int row = r0 + rl;
        float y = Yin[row * CC + lane];
        float mx = y;
        #pragma unroll
        for (int m = 32; m >= 1; m >>= 1) mx = fmaxf(mx, __shfl_xor(mx, m, 64));
        float e = __expf(y - mx);
        float s = e;
        #pragma unroll
        for (int m = 32; m >= 1; m >>= 1) s += __shfl_xor(s, m, 64);
        float ys = e / s;
        Ys[row * CC + lane] = ys;
        lds_t[lane][rl] = ys;
        nwc_acc += ys;
    }
    nwc_lds[w][lane] = nwc_acc;
    __syncthreads();
    if (t < 64)
        nwc_part[b * 64 + t] = nwc_lds[0][t] + nwc_lds[1][t] + nwc_lds[2][t] + nwc_lds[3][t];
    // write YsT bf16: thread t handles col c = t>>2, 16 rows starting q*16
    const int c = t >> 2, q = t & 3;
    unsigned short tmp[16];
    #pragma unroll
    for (int i = 0; i < 16; ++i) {
        float v = lds_t[c][q * 16 + i];
        tmp[i] = __builtin_bit_cast(unsigned short, (__bf16)v);
    }
    us8* dst = (us8*)(&YsT[(size_t)c * NN + r0 + q * 16]);
    dst[0] = *(us8*)(&tmp[0]);
    dst[1] = *(us8*)(&tmp[8]);
}

// ---------------- kernel 2: Bpart[kb] = A[:, kchunk] * Ys[kchunk, :]
// Double-buffered LDS, width-16 global_load_lds WAVE-SPLIT (6 VMEM per wave
// per step), issue-early staging (2-phase minimum recipe): STAGE(next) before
// compute(cur), one __syncthreads per step. Swizzle via pre-swizzled global
// source + XOR on read (both-sides rule). A kept fp32 in LDS, converted on
// the read side; edge sum accumulated from read-side fragments.
__global__ __launch_bounds__(256) void k2_gemm(const float* __restrict__ A,
                                               const unsigned short* __restrict__ YsT,
                                               float* __restrict__ Bpart,
                                               float* __restrict__ edges_part) {
    __shared__ __align__(16) float ldsA[2][4096];            // 2 x 16 KB
    __shared__ __align__(16) unsigned short ldsB[2][4096];   // 2 x 8 KB
    __shared__ float ered[4];
    const int t = threadIdx.x;
    const int w = t >> 6, lane = t & 63;
    const int rb = blockIdx.x;   // 0..127 row block
    const int kb = blockIdx.y;   // 0..7   k split
    const int row0 = rb * 64;
    const int k0 = kb * KCHUNK;
    const int lq = lane >> 4;    // 0..3
    const int l15 = lane & 15;   // row/col within 16-tile

    // staging lane roles (gload_lds: lane j writes LDS base + j*16B)
    const int ar  = lane >> 4;   // A: row offset within 4-row group
    const int ach = lane & 15;   // A: 16B chunk within row (4 floats)
    const int bc  = lane >> 3;   // B: col offset within 8-col group
    const int bch = lane & 7;    // B: 16B chunk within col (8 bf16)

    float esum = 0.f;
    f32x4 acc[4] = {};

    #define STAGE(buf, s)                                                                     \
    {                                                                                         \
        const int kbase_ = k0 + (s) * BK;                                                     \
        _Pragma("unroll")                                                                     \
        for (int i_ = 0; i_ < 4; ++i_) {                                                      \
            const int p_ = w * 4 + i_;                                                        \
            const int r_ = p_ * 4 + ar;                                                       \
            const float* src_ = A + (size_t)(row0 + r_) * NN + kbase_ + ((ach ^ (r_ & 7)) << 2); \
            __builtin_amdgcn_global_load_lds(                                                 \
                (const __attribute__((address_space(1))) unsigned int*)src_,                  \
                (__attribute__((address_space(3))) unsigned int*)&ldsA[buf][p_ * 256], 16, 0, 0); \
        }                                                                                     \
        _Pragma("unroll")                                                                     \
        for (int j_ = 0; j_ < 2; ++j_) {                                                      \
            const int q_ = w * 2 + j_;                                                        \
            const int c_ = q_ * 8 + bc;                                                       \
            const unsigned short* srcb_ = YsT + (size_t)c_ * NN + kbase_ + ((bch ^ (c_ & 7)) << 3); \
            __builtin_amdgcn_global_load_lds(                                                 \
                (const __attribute__((address_space(1))) unsigned int*)srcb_,                 \
                (__attribute__((address_space(3))) unsigned int*)&ldsB[buf][q_ * 512], 16, 0, 0); \
        }                                                                                     \
    }

    STAGE(0, 0);
    __syncthreads();   // drain: tile 0 resident
    int cur = 0;

    for (int s = 0; s < NSTEPS; ++s) {
        if (s + 1 < NSTEPS) STAGE(cur ^ 1, s + 1);   // issue-early: fly during compute
        // --- compute from buffer `cur`: 2 K-slices of 32, 4 col tiles
        #pragma unroll
        for (int kk = 0; kk < 2; ++kk) {
            const int r = w * 16 + l15;
            const int cc = kk * 8 + lq * 2;          // even global chunk
            const int ch0 = cc ^ (r & 7);            // LDS chunk holding global cc
            const f32x4 fa0 = *(const f32x4*)&ldsA[cur][r * 64 + (ch0 << 2)];
            const f32x4 fa1 = *(const f32x4*)&ldsA[cur][r * 64 + ((ch0 ^ 1) << 2)];
            esum += (fa0[0] + fa0[1] + fa0[2] + fa0[3]) + (fa1[0] + fa1[1] + fa1[2] + fa1[3]);
            bf16x8 a;
            a[0] = (__bf16)fa0[0]; a[1] = (__bf16)fa0[1]; a[2] = (__bf16)fa0[2]; a[3] = (__bf16)fa0[3];
            a[4] = (__bf16)fa1[0]; a[5] = (__bf16)fa1[1]; a[6] = (__bf16)fa1[2]; a[7] = (__bf16)fa1[3];
            #pragma unroll
            for (int t4 = 0; t4 < 4; ++t4) {
                const int col = t4 * 16 + l15;
                const int chB = (kk * 4 + lq) ^ (col & 7);
                const bf16x8 bb = *(const bf16x8*)&ldsB[cur][col * 64 + (chB << 3)];
                acc[t4] = __builtin_amdgcn_mfma_f32_16x16x32_bf16(a, bb, acc[t4], 0, 0, 0);
            }
        }
        __syncthreads();   // drain vmcnt (next tile ready) + free this tile
        cur ^= 1;
    }
    #undef STAGE

    // --- write partial B: Bpart[kb][row][col]
    const size_t base = ((size_t)kb * NN + row0) * CC;
    #pragma unroll
    for (int t4 = 0; t4 < 4; ++t4) {
        const int col = t4 * 16 + l15;
        #pragma unroll
        for (int r = 0; r < 4; ++r) {
            const int grow = w * 16 + lq * 4 + r;   // D layout: row=(lane>>4)*4+reg
            Bpart[base + (size_t)grow * CC + col] = acc[t4][r];
        }
    }
    // --- edge sum reduction (deterministic)
    #pragma unroll
    for (int m = 32; m >= 1; m >>= 1) esum += __shfl_xor(esum, m, 64);
    if (lane == 0) ered[w] = esum;
    __syncthreads();
    if (t == 0) edges_part[rb * KSPLIT + kb] = ered[0] + ered[1] + ered[2] + ered[3];
}

// ---------------- kernel 3: partial M over 32-row chunks x 2 kb-halves
// Mpart[b*2+ph] = Ys[chunk]^T * (sum of 4 Bparts)[chunk]   (M linear in B)
__global__ __launch_bounds__(256) void k3_mpart(const float* __restrict__ Bpart,
                                                const float* __restrict__ Ys,
                                                float* __restrict__ Mpart) {
    __shared__ float bl[2048];   // B rows [32][64]
    __shared__ float yl[2048];   // Ys rows [32][64]
    const int t = threadIdx.x;
    const int b = blockIdx.x;    // 0..255  (32-row chunk)
    const int ph = blockIdx.y;   // 0..1    (which 4 of the 8 k-splits)
    const int r0 = b * 32;
    for (int k = 0; k < 8; ++k) {
        const int e = k * 256 + t;
        const int i = e >> 6, c = e & 63;
        const size_t off = ((size_t)(r0 + i)) * CC + c;
        float s = 0.f;
        #pragma unroll
        for (int j = 0; j < 4; ++j) s += Bpart[(size_t)(ph * 4 + j) * NN * CC + off];
        bl[e] = s;
        yl[e] = Ys[off];
    }
    __syncthreads();
    const int w = t >> 6, lane = t & 63;
    float acc[16];
    #pragma unroll
    for (int k = 0; k < 16; ++k) acc[k] = 0.f;
    for (int i = 0; i < 32; ++i) {
        const float bv = bl[i * 64 + lane];
        #pragma unroll
        for (int k = 0; k < 16; ++k)
            acc[k] += yl[i * 64 + 4 * k + w] * bv;   // c1 = 4k + w uniform per wave -> broadcast
    }
    #pragma unroll
    for (int k = 0; k < 16; ++k)
        Mpart[(size_t)(b * 2 + ph) * 4096 + k * 256 + t] = acc[k];   // index == c1*64 + c2
}

// ---------------- kernel 4: reduce Mpart (512 slabs) -> M[64][64]
__global__ __launch_bounds__(256) void k4_reduce(const float* __restrict__ Mpart,
                                                 float* __restrict__ M) {
    const int e = blockIdx.x * 256 + threadIdx.x;   // grid 16
    float s = 0.f;
    for (int b = 0; b < 512; ++b) s += Mpart[(size_t)b * 4096 + e];
    M[e] = s;
}

// ---------------- kernel 5: final scalar
__global__ __launch_bounds__(256) void k5_final(const float* __restrict__ M,
                                                const float* __restrict__ nwc_part,
                                                const float* __restrict__ edges_part,
                                                float* __restrict__ out) {
    __shared__ float red[256];
    const int t = threadIdx.x;
    float se = 0.f, st = 0.f, sc = 0.f;
    for (int i = t; i < 128 * KSPLIT; i += 256) se += edges_part[i];
    for (int e = t; e < 4096; e += 256) {
        const int c1 = e >> 6, c2 = e & 63;
        if (c2 > c1) st += M[e];
    }
    if (t < 64) {
        float nwc = 0.f;
        for (int b = 0; b < 128; ++b) nwc += nwc_part[b * 64 + t];
        const float me = (nwc * (nwc - 1.0f) + 1e-8f) * 0.5f;
        sc = M[t * 65] / me;
    }
    // three block reductions
    red[t] = se; __syncthreads();
    for (int s = 128; s >= 1; s >>= 1) { if (t < s) red[t] += red[t + s]; __syncthreads(); }
    const float tot_e = red[0]; __syncthreads();
    red[t] = st; __syncthreads();
    for (int s = 128; s >= 1; s >>= 1) { if (t < s) red[t] += red[t + s]; __syncthreads(); }
    const float tot_triu = red[0]; __syncthreads();
    red[t] = sc; __syncthreads();
    for (int s = 128; s >= 1; s >>= 1) { if (t < s) red[t] += red[t + s]; __syncthreads(); }
    const float cohesion = red[0];
    if (t == 0)
        out[0] = -cohesion + tot_triu / (tot_e + 1e-9f);
}

extern "C" void kernel_launch(void* const* d_in, const int* in_sizes, int n_in,
                              void* d_out, int out_size, void* d_ws, size_t ws_size,
                              hipStream_t stream) {
    const float* A   = (const float*)d_in[0];
    const float* Yin = (const float*)d_in[1];
    float* out = (float*)d_out;
    char* ws = (char*)d_ws;
    // workspace layout (bytes)
    float*          Ys         = (float*)(ws + 0);                  // 2 MB
    unsigned short* YsT        = (unsigned short*)(ws + 2097152);   // 1 MB
    float*          nwc_part   = (float*)(ws + 3145728);            // 32 KB
    float*          edges_part = (float*)(ws + 3178496);            // 4 KB
    float*          Bpart      = (float*)(ws + 4194304);            // 16 MB
    float*          Mpart      = (float*)(ws + 20971520);           // 8 MB (512 x 16 KB)
    float*          M          = (float*)(ws + 29360128);           // 16 KB

    k1_softmax<<<128, 256, 0, stream>>>(Yin, Ys, YsT, nwc_part);
    k2_gemm<<<dim3(128, KSPLIT), 256, 0, stream>>>(A, YsT, Bpart, edges_part);
    k3_mpart<<<dim3(256, 2), 256, 0, stream>>>(Bpart, Ys, Mpart);
    k4_reduce<<<16, 256, 0, stream>>>(Mpart, M);
    k5_final<<<1, 256, 0, stream>>>(M, nwc_part, edges_part, out);
}